// Round 1
// baseline (1435.357 us; speedup 1.0000x reference)
//
#include <hip/hip_runtime.h>
#include <hip/hip_bf16.h>

#define B_   2
#define T_   2048
#define C_   1024
#define H_   16
#define KV_  4
#define HD_  64
#define M_   (B_*T_)     // 4096 tokens
#define NQKV_ 1536       // 1024 q + 256 k + 256 v

typedef __bf16 bf16x8 __attribute__((ext_vector_type(8)));
typedef float  f32x4  __attribute__((ext_vector_type(4)));

static __device__ __forceinline__ unsigned short f2bf(float f) {
    __hip_bfloat16 h = __float2bfloat16(f);
    return __builtin_bit_cast(unsigned short, h);
}

// ---------------------------------------------------------------- cast x -> bf16
__global__ void cast_x_kernel(const float* __restrict__ x, unsigned short* __restrict__ xb) {
    int i = (blockIdx.x * 256 + threadIdx.x) * 4;
    float4 v = *(const float4*)(x + i);
    unsigned short o0 = f2bf(v.x), o1 = f2bf(v.y), o2 = f2bf(v.z), o3 = f2bf(v.w);
    ushort4 o = make_ushort4(o0, o1, o2, o3);
    *(ushort4*)(xb + i) = o;
}

// --------------------------------------- transpose + cast: W (K x N) -> Wt (N x K) bf16
__global__ void transpose_cast_kernel(const float* __restrict__ src, unsigned short* __restrict__ dst,
                                      int K, int N) {
    __shared__ float tile[32][33];
    int k0 = blockIdx.x * 32, n0 = blockIdx.y * 32;
    int lr = threadIdx.x >> 5, lc = threadIdx.x & 31;
    #pragma unroll
    for (int i = 0; i < 4; i++) {
        int r = lr + i * 8;
        tile[r][lc] = src[(k0 + r) * N + n0 + lc];
    }
    __syncthreads();
    #pragma unroll
    for (int i = 0; i < 4; i++) {
        int r = lr + i * 8;
        dst[(n0 + r) * K + k0 + lc] = f2bf(tile[lc][r]);
    }
}

// ------------------------------------------------ bf16 MFMA GEMM: C = A (MxK) * Bt^T (NxK)
// 64x64 block tile, 4 waves, wave w does rows w*16..w*16+15 x 64 cols, BK=32.
__global__ __launch_bounds__(256) void gemm_bt_kernel(const unsigned short* __restrict__ A,
                                                      const unsigned short* __restrict__ Bt,
                                                      float* __restrict__ Cm,
                                                      int Mi, int Ni, int Ki) {
    __shared__ __align__(16) unsigned short As[64 * 32];
    __shared__ __align__(16) unsigned short Bs[64 * 32];
    int m0 = blockIdx.x * 64, n0 = blockIdx.y * 64;
    int tid  = threadIdx.x;
    int w    = tid >> 6, lane = tid & 63;
    int srow = tid >> 2, skoff = (tid & 3) * 8;
    int mr   = lane & 15, quad = lane >> 4;

    f32x4 acc[4];
    #pragma unroll
    for (int nt = 0; nt < 4; nt++) acc[nt] = (f32x4){0.f, 0.f, 0.f, 0.f};

    for (int k0 = 0; k0 < Ki; k0 += 32) {
        *(uint4*)&As[srow * 32 + skoff] = *(const uint4*)&A[(size_t)(m0 + srow) * Ki + k0 + skoff];
        *(uint4*)&Bs[srow * 32 + skoff] = *(const uint4*)&Bt[(size_t)(n0 + srow) * Ki + k0 + skoff];
        __syncthreads();
        bf16x8 a = *(const bf16x8*)&As[(w * 16 + mr) * 32 + quad * 8];
        #pragma unroll
        for (int nt = 0; nt < 4; nt++) {
            bf16x8 b = *(const bf16x8*)&Bs[(nt * 16 + mr) * 32 + quad * 8];
            acc[nt] = __builtin_amdgcn_mfma_f32_16x16x32_bf16(a, b, acc[nt], 0, 0, 0);
        }
        __syncthreads();
    }
    // C/D layout: col = lane&15, row = quad*4 + r  (verified m89/m91)
    #pragma unroll
    for (int nt = 0; nt < 4; nt++)
        #pragma unroll
        for (int r = 0; r < 4; r++)
            Cm[(size_t)(m0 + w * 16 + quad * 4 + r) * Ni + n0 + nt * 16 + mr] = acc[nt][r];
}

// ------------------------------------------------ RoPE + RMSNorm on q (16 heads) + k (4 heads)
// one wave per (token, head) row of 64
__global__ void rope_rms_kernel(float* __restrict__ qkv,
                                const float* __restrict__ cosb, const float* __restrict__ sinb) {
    int rid  = blockIdx.x * 4 + (threadIdx.x >> 6);
    int lane = threadIdx.x & 63;
    int token = rid / 20, head = rid % 20;     // 20 = H + KV
    int t = token & (T_ - 1);
    float* p = qkv + (size_t)token * NQKV_ + (head < H_ ? head * 64 : 1024 + (head - H_) * 64);
    int i  = lane & 31;
    float c = cosb[t * 32 + i], s = sinb[t * 32 + i];
    float out;
    if (lane < 32) {
        float x1 = p[lane], x2 = p[lane + 32];
        out = x1 * c + x2 * s;
    } else {
        float x1 = p[lane - 32], x2 = p[lane];
        out = -x1 * s + x2 * c;
    }
    float sq = out * out;
    #pragma unroll
    for (int msk = 1; msk < 64; msk <<= 1) sq += __shfl_xor(sq, msk, 64);
    float r = rsqrtf(sq * (1.0f / 64.0f) + 1e-6f);
    p[lane] = out * r;
}

// ------------------------------------------------ flash attention (fp32), 64-query tiles
// 256 threads = 64 rows x 4 lanes; LDS stride 68 floats (float4-aligned, spreads banks)
__global__ __launch_bounds__(256) void attn_kernel(const float* __restrict__ qkv,
                                                   unsigned short* __restrict__ yb) {
    __shared__ __align__(16) float Qs[64 * 68];
    __shared__ __align__(16) float KVs[64 * 68];
    __shared__ __align__(16) float Ps[64 * 68];
    int qt = blockIdx.x & 31;           // T/64 = 32 query tiles
    int bh = blockIdx.x >> 5;
    int b = bh >> 4, h = bh & 15, kvh = h >> 2;   // n_rep = 4
    int tid = threadIdx.x;
    int row = tid >> 2, j = tid & 3;
    int tau0 = qt * 64;
    const float scale = 0.125f;          // 1/sqrt(64), folded into Q

    #pragma unroll
    for (int i = 0; i < 16; i++) {
        int idx = tid + i * 256;
        int r = idx >> 6, d = idx & 63;
        Qs[r * 68 + d] = qkv[((size_t)(b * T_ + tau0 + r)) * NQKV_ + h * 64 + d] * scale;
    }

    float m = -1e30f, l = 0.f;
    float o[16];
    #pragma unroll
    for (int c = 0; c < 16; c++) o[c] = 0.f;

    for (int kt = 0; kt <= qt; kt++) {
        __syncthreads();
        // stage K tile
        #pragma unroll
        for (int i = 0; i < 16; i++) {
            int idx = tid + i * 256;
            int r = idx >> 6, d = idx & 63;
            KVs[r * 68 + d] = qkv[((size_t)(b * T_ + kt * 64 + r)) * NQKV_ + 1024 + kvh * 64 + d];
        }
        __syncthreads();
        // scores: this thread covers keys j*16 .. j*16+15 for its row
        float s[16];
        #pragma unroll
        for (int i = 0; i < 16; i++) s[i] = 0.f;
        #pragma unroll 4
        for (int d4 = 0; d4 < 16; d4++) {
            float4 q4 = *(const float4*)&Qs[row * 68 + d4 * 4];
            #pragma unroll
            for (int i = 0; i < 16; i++) {
                float4 k4 = *(const float4*)&KVs[(j * 16 + i) * 68 + d4 * 4];
                s[i] += q4.x * k4.x + q4.y * k4.y + q4.z * k4.z + q4.w * k4.w;
            }
        }
        if (kt == qt) {
            #pragma unroll
            for (int i = 0; i < 16; i++)
                if (j * 16 + i > row) s[i] = -1e30f;
        }
        float mx = s[0];
        #pragma unroll
        for (int i = 1; i < 16; i++) mx = fmaxf(mx, s[i]);
        mx = fmaxf(mx, __shfl_xor(mx, 1, 64));
        mx = fmaxf(mx, __shfl_xor(mx, 2, 64));
        float mnew  = fmaxf(m, mx);
        float alpha = __expf(m - mnew);
        float psum = 0.f;
        #pragma unroll
        for (int i = 0; i < 16; i++) { s[i] = __expf(s[i] - mnew); psum += s[i]; }
        psum += __shfl_xor(psum, 1, 64);
        psum += __shfl_xor(psum, 2, 64);
        l = l * alpha + psum;
        m = mnew;
        #pragma unroll
        for (int c = 0; c < 16; c++) o[c] *= alpha;
        #pragma unroll
        for (int i4 = 0; i4 < 4; i4++) {
            float4 pv = make_float4(s[i4 * 4], s[i4 * 4 + 1], s[i4 * 4 + 2], s[i4 * 4 + 3]);
            *(float4*)&Ps[row * 68 + j * 16 + i4 * 4] = pv;
        }
        __syncthreads();
        // stage V tile (reuse K buffer)
        #pragma unroll
        for (int i = 0; i < 16; i++) {
            int idx = tid + i * 256;
            int r = idx >> 6, d = idx & 63;
            KVs[r * 68 + d] = qkv[((size_t)(b * T_ + kt * 64 + r)) * NQKV_ + 1280 + kvh * 64 + d];
        }
        __syncthreads();
        // PV: this thread accumulates dims j*16 .. j*16+15 for its row
        #pragma unroll 8
        for (int kk = 0; kk < 64; kk++) {
            float p = Ps[row * 68 + kk];
            #pragma unroll
            for (int c4 = 0; c4 < 4; c4++) {
                float4 v4 = *(const float4*)&KVs[kk * 68 + j * 16 + c4 * 4];
                o[c4 * 4 + 0] += p * v4.x;
                o[c4 * 4 + 1] += p * v4.y;
                o[c4 * 4 + 2] += p * v4.z;
                o[c4 * 4 + 3] += p * v4.w;
            }
        }
    }
    float inv = 1.0f / l;
    #pragma unroll
    for (int c = 0; c < 16; c++)
        yb[((size_t)(b * T_ + tau0 + row)) * C_ + h * 64 + j * 16 + c] = f2bf(o[c] * inv);
}

// ---------------------------------------------------------------- launch
extern "C" void kernel_launch(void* const* d_in, const int* in_sizes, int n_in,
                              void* d_out, int out_size, void* d_ws, size_t ws_size,
                              hipStream_t stream) {
    const float* x    = (const float*)d_in[0];
    const float* cosb = (const float*)d_in[1];
    const float* sinb = (const float*)d_in[2];
    const float* Wq   = (const float*)d_in[3];
    const float* Wk   = (const float*)d_in[4];
    const float* Wv   = (const float*)d_in[5];
    const float* Wo   = (const float*)d_in[6];
    float* out = (float*)d_out;

    char* ws = (char*)d_ws;
    unsigned short* xb    = (unsigned short*)(ws);                              // 4096*1024*2 = 8 MB
    unsigned short* wtqkv = (unsigned short*)(ws + 8388608);                    // 1536*1024*2 = 3 MB
    unsigned short* wto   = (unsigned short*)(ws + 8388608 + 3145728);          // 1024*1024*2 = 2 MB
    float*          qkv   = (float*)(ws + 8388608 + 3145728 + 2097152);         // 4096*1536*4 = 24 MB
    unsigned short* yb    = (unsigned short*)(ws + 8388608 + 3145728 + 2097152 + 25165824); // 8 MB

    // 1. casts / transposes
    cast_x_kernel<<<4096, 256, 0, stream>>>(x, xb);
    transpose_cast_kernel<<<dim3(32, 32), 256, 0, stream>>>(Wq, wtqkv,               1024, 1024);
    transpose_cast_kernel<<<dim3(32, 8),  256, 0, stream>>>(Wk, wtqkv + 1024 * 1024, 1024, 256);
    transpose_cast_kernel<<<dim3(32, 8),  256, 0, stream>>>(Wv, wtqkv + 1280 * 1024, 1024, 256);
    transpose_cast_kernel<<<dim3(32, 32), 256, 0, stream>>>(Wo, wto,                 1024, 1024);
    // 2. fused QKV projection (bf16 MFMA, fp32 out)
    gemm_bt_kernel<<<dim3(64, 24), 256, 0, stream>>>(xb, wtqkv, qkv, M_, NQKV_, C_);
    // 3. RoPE + RMSNorm on q,k rows
    rope_rms_kernel<<<(M_ * 20) / 4, 256, 0, stream>>>(qkv, cosb, sinb);
    // 4. causal flash attention, writes y as bf16
    attn_kernel<<<B_ * H_ * (T_ / 64), 256, 0, stream>>>(qkv, yb);
    // 5. output projection
    gemm_bt_kernel<<<dim3(64, 16), 256, 0, stream>>>(yb, wto, out, M_, C_, C_);
}

// Round 2
// 281.388 us; speedup vs baseline: 5.1010x; 5.1010x over previous
//
#include <hip/hip_runtime.h>
#include <hip/hip_bf16.h>

#define B_   2
#define T_   2048
#define C_   1024
#define H_   16
#define KV_  4
#define HD_  64
#define M_   (B_*T_)     // 4096 tokens
#define NQKV_ 1536       // 1024 q + 256 k + 256 v
#define ST_  72          // LDS row stride (bf16 elems): 144 B = 9*16 B

typedef __bf16 bf16x8 __attribute__((ext_vector_type(8)));
typedef float  f32x4  __attribute__((ext_vector_type(4)));

static __device__ __forceinline__ unsigned short f2bf(float f) {
    __hip_bfloat16 h = __float2bfloat16(f);
    return __builtin_bit_cast(unsigned short, h);
}
static __device__ __forceinline__ float bf2f(unsigned short u) {
    __hip_bfloat16 h = __builtin_bit_cast(__hip_bfloat16, u);
    return __bfloat162float(h);
}

// ---------------------------------------------------------------- cast x -> bf16
__global__ void cast_x_kernel(const float* __restrict__ x, unsigned short* __restrict__ xb) {
    int i = (blockIdx.x * 256 + threadIdx.x) * 4;
    float4 v = *(const float4*)(x + i);
    ushort4 o = make_ushort4(f2bf(v.x), f2bf(v.y), f2bf(v.z), f2bf(v.w));
    *(ushort4*)(xb + i) = o;
}

// --------------------------------------- transpose + cast: W (K x N) -> Wt (N x K) bf16
__global__ void transpose_cast_kernel(const float* __restrict__ src, unsigned short* __restrict__ dst,
                                      int K, int N) {
    __shared__ float tile[32][33];
    int k0 = blockIdx.x * 32, n0 = blockIdx.y * 32;
    int lr = threadIdx.x >> 5, lc = threadIdx.x & 31;
    #pragma unroll
    for (int i = 0; i < 4; i++) {
        int r = lr + i * 8;
        tile[r][lc] = src[(k0 + r) * N + n0 + lc];
    }
    __syncthreads();
    #pragma unroll
    for (int i = 0; i < 4; i++) {
        int r = lr + i * 8;
        dst[(n0 + r) * K + k0 + lc] = f2bf(tile[lc][r]);
    }
}

// ------------------------------------------------ bf16 MFMA GEMM: C = A (MxK) * Bt^T (NxK)
// 64x64 block tile, 4 waves; templated output (fp32 or bf16)
template <typename T>
__global__ __launch_bounds__(256) void gemm_bt_kernel(const unsigned short* __restrict__ A,
                                                      const unsigned short* __restrict__ Bt,
                                                      T* __restrict__ Cm,
                                                      int Ni, int Ki) {
    __shared__ __align__(16) unsigned short As[64 * 32];
    __shared__ __align__(16) unsigned short Bs[64 * 32];
    int m0 = blockIdx.x * 64, n0 = blockIdx.y * 64;
    int tid  = threadIdx.x;
    int w    = tid >> 6, lane = tid & 63;
    int srow = tid >> 2, skoff = (tid & 3) * 8;
    int mr   = lane & 15, quad = lane >> 4;

    f32x4 acc[4];
    #pragma unroll
    for (int nt = 0; nt < 4; nt++) acc[nt] = (f32x4){0.f, 0.f, 0.f, 0.f};

    for (int k0 = 0; k0 < Ki; k0 += 32) {
        *(uint4*)&As[srow * 32 + skoff] = *(const uint4*)&A[(size_t)(m0 + srow) * Ki + k0 + skoff];
        *(uint4*)&Bs[srow * 32 + skoff] = *(const uint4*)&Bt[(size_t)(n0 + srow) * Ki + k0 + skoff];
        __syncthreads();
        bf16x8 a = *(const bf16x8*)&As[(w * 16 + mr) * 32 + quad * 8];
        #pragma unroll
        for (int nt = 0; nt < 4; nt++) {
            bf16x8 b = *(const bf16x8*)&Bs[(nt * 16 + mr) * 32 + quad * 8];
            acc[nt] = __builtin_amdgcn_mfma_f32_16x16x32_bf16(a, b, acc[nt], 0, 0, 0);
        }
        __syncthreads();
    }
    // C/D layout: col = lane&15, row = quad*4 + r
    #pragma unroll
    for (int nt = 0; nt < 4; nt++)
        #pragma unroll
        for (int r = 0; r < 4; r++) {
            size_t idx = (size_t)(m0 + w * 16 + quad * 4 + r) * Ni + n0 + nt * 16 + mr;
            if constexpr (sizeof(T) == 2) Cm[idx] = f2bf(acc[nt][r]);
            else                          Cm[idx] = acc[nt][r];
        }
}

// ------------------------------------------------ RoPE + RMSNorm on q (16 heads, *0.125) + k (4 heads)
// in-place on bf16 qkv; one wave per (token, head) row of 64
__global__ void rope_rms_kernel(unsigned short* __restrict__ qkvb,
                                const float* __restrict__ cosb, const float* __restrict__ sinb) {
    int rid  = blockIdx.x * 4 + (threadIdx.x >> 6);
    int lane = threadIdx.x & 63;
    int token = rid / 20, head = rid % 20;     // 20 = H + KV; layout offset = head*64 for all
    int t = token & (T_ - 1);
    unsigned short* p = qkvb + (size_t)token * NQKV_ + head * 64;
    int i  = lane & 31;
    float c = cosb[t * 32 + i], s = sinb[t * 32 + i];
    float out;
    if (lane < 32) {
        float x1 = bf2f(p[lane]), x2 = bf2f(p[lane + 32]);
        out = x1 * c + x2 * s;
    } else {
        float x1 = bf2f(p[lane - 32]), x2 = bf2f(p[lane]);
        out = -x1 * s + x2 * c;
    }
    float sq = out * out;
    #pragma unroll
    for (int msk = 1; msk < 64; msk <<= 1) sq += __shfl_xor(sq, msk, 64);
    float r = rsqrtf(sq * (1.0f / 64.0f) + 1e-6f);
    float scale = (head < H_) ? 0.125f : 1.0f;   // fold attn 1/sqrt(64) into q
    p[lane] = f2bf(out * r * scale);
}

// ------------------------------------------------ MFMA flash attention (bf16 in/out, fp32 accum)
// block = (b, h, 64-query tile); 4 waves; wave w owns query rows w*16..+15
__global__ __launch_bounds__(256) void attn_kernel(const unsigned short* __restrict__ qkvb,
                                                   unsigned short* __restrict__ yb) {
    __shared__ __align__(16) unsigned short Qs[64 * ST_];
    __shared__ __align__(16) unsigned short Ks[64 * ST_];
    __shared__ __align__(16) unsigned short Vts[64 * ST_];  // V transposed: [dim][key]
    __shared__ __align__(16) unsigned short Ps[64 * ST_];

    int qt = blockIdx.x & 31;            // T/64 query tiles
    int bh = blockIdx.x >> 5;
    int b = bh >> 4, h = bh & 15, kvh = h >> 2;
    int tid  = threadIdx.x;
    int w    = tid >> 6, lane = tid & 63;
    int col  = lane & 15, quad = lane >> 4;
    int tau0 = qt * 64;
    size_t rowbase = (size_t)(b * T_) * NQKV_;

    // stage Q (scaled already by rope_rms)
    #pragma unroll
    for (int i = 0; i < 2; i++) {
        int idx = tid + i * 256;
        int r = idx >> 3, d8 = idx & 7;
        *(uint4*)&Qs[r * ST_ + d8 * 8] =
            *(const uint4*)&qkvb[rowbase + (size_t)(tau0 + r) * NQKV_ + h * 64 + d8 * 8];
    }

    float mrow[4], lrow[4];
    #pragma unroll
    for (int r = 0; r < 4; r++) { mrow[r] = -1e30f; lrow[r] = 0.f; }
    f32x4 o[4];
    #pragma unroll
    for (int nt = 0; nt < 4; nt++) o[nt] = (f32x4){0.f, 0.f, 0.f, 0.f};

    for (int kt = 0; kt <= qt; kt++) {
        __syncthreads();   // protect Ks/Vts/Ps from previous iteration's readers
        // stage K [key][d]
        #pragma unroll
        for (int i = 0; i < 2; i++) {
            int idx = tid + i * 256;
            int r = idx >> 3, d8 = idx & 7;
            *(uint4*)&Ks[r * ST_ + d8 * 8] =
                *(const uint4*)&qkvb[rowbase + (size_t)(kt * 64 + r) * NQKV_ + 1024 + kvh * 64 + d8 * 8];
        }
        // stage V transposed [d][key]: lane = key so each write step spans all banks
        #pragma unroll
        for (int i = 0; i < 2; i++) {
            int d8 = w + i * 4;
            int key = lane;
            uint4 v8 = *(const uint4*)&qkvb[rowbase + (size_t)(kt * 64 + key) * NQKV_ + 1280 + kvh * 64 + d8 * 8];
            const unsigned short* vp = (const unsigned short*)&v8;
            #pragma unroll
            for (int j = 0; j < 8; j++)
                Vts[(d8 * 8 + j) * ST_ + key] = vp[j];
        }
        __syncthreads();

        // S = Q K^T  (16x64 per wave)
        f32x4 sacc[4];
        #pragma unroll
        for (int nt = 0; nt < 4; nt++) sacc[nt] = (f32x4){0.f, 0.f, 0.f, 0.f};
        #pragma unroll
        for (int step = 0; step < 2; step++) {
            bf16x8 a = *(const bf16x8*)&Qs[(w * 16 + col) * ST_ + quad * 8 + step * 32];
            #pragma unroll
            for (int nt = 0; nt < 4; nt++) {
                bf16x8 bfr = *(const bf16x8*)&Ks[(nt * 16 + col) * ST_ + quad * 8 + step * 32];
                sacc[nt] = __builtin_amdgcn_mfma_f32_16x16x32_bf16(a, bfr, sacc[nt], 0, 0, 0);
            }
        }
        // causal mask on the diagonal tile
        if (kt == qt) {
            #pragma unroll
            for (int nt = 0; nt < 4; nt++)
                #pragma unroll
                for (int r = 0; r < 4; r++)
                    if (nt * 16 + col > w * 16 + quad * 4 + r) sacc[nt][r] = -1e30f;
        }
        // online softmax per row (lane holds rows quad*4+r, cols col across nt)
        float alpha[4];
        #pragma unroll
        for (int r = 0; r < 4; r++) {
            float mx = fmaxf(fmaxf(sacc[0][r], sacc[1][r]), fmaxf(sacc[2][r], sacc[3][r]));
            mx = fmaxf(mx, __shfl_xor(mx, 1, 64));
            mx = fmaxf(mx, __shfl_xor(mx, 2, 64));
            mx = fmaxf(mx, __shfl_xor(mx, 4, 64));
            mx = fmaxf(mx, __shfl_xor(mx, 8, 64));
            float mnew = fmaxf(mrow[r], mx);
            alpha[r] = __expf(mrow[r] - mnew);
            float rs = 0.f;
            #pragma unroll
            for (int nt = 0; nt < 4; nt++) {
                float pv = __expf(sacc[nt][r] - mnew);
                sacc[nt][r] = pv;
                rs += pv;
            }
            rs += __shfl_xor(rs, 1, 64);
            rs += __shfl_xor(rs, 2, 64);
            rs += __shfl_xor(rs, 4, 64);
            rs += __shfl_xor(rs, 8, 64);
            lrow[r] = lrow[r] * alpha[r] + rs;
            mrow[r] = mnew;
        }
        // write P (bf16) to LDS in natural [query][key] layout
        #pragma unroll
        for (int nt = 0; nt < 4; nt++)
            #pragma unroll
            for (int r = 0; r < 4; r++)
                Ps[(w * 16 + quad * 4 + r) * ST_ + nt * 16 + col] = f2bf(sacc[nt][r]);
        // rescale O
        #pragma unroll
        for (int nt = 0; nt < 4; nt++)
            #pragma unroll
            for (int r = 0; r < 4; r++)
                o[nt][r] *= alpha[r];
        __syncthreads();

        // O += P V   (A = P[q][key], B = V^T[d][key])
        #pragma unroll
        for (int step = 0; step < 2; step++) {
            bf16x8 a = *(const bf16x8*)&Ps[(w * 16 + col) * ST_ + quad * 8 + step * 32];
            #pragma unroll
            for (int nt = 0; nt < 4; nt++) {
                bf16x8 bfr = *(const bf16x8*)&Vts[(nt * 16 + col) * ST_ + quad * 8 + step * 32];
                o[nt] = __builtin_amdgcn_mfma_f32_16x16x32_bf16(a, bfr, o[nt], 0, 0, 0);
            }
        }
    }

    #pragma unroll
    for (int r = 0; r < 4; r++) {
        float inv = 1.0f / lrow[r];
        size_t row = (size_t)(b * T_ + tau0 + w * 16 + quad * 4 + r) * C_ + h * 64;
        #pragma unroll
        for (int nt = 0; nt < 4; nt++)
            yb[row + nt * 16 + col] = f2bf(o[nt][r] * inv);
    }
}

// ---------------------------------------------------------------- launch
extern "C" void kernel_launch(void* const* d_in, const int* in_sizes, int n_in,
                              void* d_out, int out_size, void* d_ws, size_t ws_size,
                              hipStream_t stream) {
    const float* x    = (const float*)d_in[0];
    const float* cosb = (const float*)d_in[1];
    const float* sinb = (const float*)d_in[2];
    const float* Wq   = (const float*)d_in[3];
    const float* Wk   = (const float*)d_in[4];
    const float* Wv   = (const float*)d_in[5];
    const float* Wo   = (const float*)d_in[6];
    float* out = (float*)d_out;

    char* ws = (char*)d_ws;
    unsigned short* xb    = (unsigned short*)(ws);                       // 8 MB
    unsigned short* wtqkv = (unsigned short*)(ws + (8u << 20));          // 3 MB
    unsigned short* wto   = (unsigned short*)(ws + (11u << 20));         // 2 MB
    unsigned short* qkvb  = (unsigned short*)(ws + (13u << 20));         // 4096*1536*2 = 12 MB
    unsigned short* yb    = (unsigned short*)(ws + (25u << 20));         // 8 MB

    cast_x_kernel<<<4096, 256, 0, stream>>>(x, xb);
    transpose_cast_kernel<<<dim3(32, 32), 256, 0, stream>>>(Wq, wtqkv,               1024, 1024);
    transpose_cast_kernel<<<dim3(32, 8),  256, 0, stream>>>(Wk, wtqkv + 1024 * 1024, 1024, 256);
    transpose_cast_kernel<<<dim3(32, 8),  256, 0, stream>>>(Wv, wtqkv + 1280 * 1024, 1024, 256);
    transpose_cast_kernel<<<dim3(32, 32), 256, 0, stream>>>(Wo, wto,                 1024, 1024);
    // QKV projection -> bf16
    gemm_bt_kernel<unsigned short><<<dim3(64, 24), 256, 0, stream>>>(xb, wtqkv, qkvb, NQKV_, C_);
    // RoPE + RMSNorm in place (q scaled by 0.125)
    rope_rms_kernel<<<(M_ * 20) / 4, 256, 0, stream>>>(qkvb, cosb, sinb);
    // MFMA flash attention -> yb (bf16)
    attn_kernel<<<B_ * H_ * (T_ / 64), 256, 0, stream>>>(qkvb, yb);
    // output projection -> fp32 out
    gemm_bt_kernel<float><<<dim3(64, 16), 256, 0, stream>>>(yb, wto, out, 1024, 1024);
}

// Round 3
// 222.411 us; speedup vs baseline: 6.4536x; 1.2652x over previous
//
#include <hip/hip_runtime.h>
#include <hip/hip_bf16.h>

#define B_   2
#define T_   2048
#define C_   1024
#define H_   16
#define KV_  4
#define HD_  64
#define M_   (B_*T_)     // 4096 tokens
#define NQKV_ 1536       // 1024 q + 256 k + 256 v
#define ST_  72          // LDS row stride (bf16 elems): 144 B

typedef __bf16 bf16x8 __attribute__((ext_vector_type(8)));
typedef float  f32x4  __attribute__((ext_vector_type(4)));

static __device__ __forceinline__ unsigned short f2bf(float f) {
    __hip_bfloat16 h = __float2bfloat16(f);
    return __builtin_bit_cast(unsigned short, h);
}
static __device__ __forceinline__ float bf2f(unsigned short u) {
    __hip_bfloat16 h = __builtin_bit_cast(__hip_bfloat16, u);
    return __bfloat162float(h);
}

// ---------------------------------------------------------------- cast x -> bf16
__global__ void cast_x_kernel(const float* __restrict__ x, unsigned short* __restrict__ xb) {
    int i = (blockIdx.x * 256 + threadIdx.x) * 4;
    float4 v = *(const float4*)(x + i);
    ushort4 o = make_ushort4(f2bf(v.x), f2bf(v.y), f2bf(v.z), f2bf(v.w));
    *(ushort4*)(xb + i) = o;
}

// --------------------------------------- all 4 weight transposes in one launch
// W (1024 x N) -> Wt (N x 1024) bf16
__global__ void transpose4_kernel(const float* __restrict__ Wq, const float* __restrict__ Wk,
                                  const float* __restrict__ Wv, const float* __restrict__ Wo,
                                  unsigned short* __restrict__ wtqkv, unsigned short* __restrict__ wto) {
    __shared__ float tile[32][33];
    int bid = blockIdx.x;
    const float* src; unsigned short* dst; int s, nlog;
    if (bid < 1024)      { src = Wq; dst = wtqkv;               s = bid;        nlog = 5; }
    else if (bid < 1280) { src = Wk; dst = wtqkv + 1024 * 1024; s = bid - 1024; nlog = 3; }
    else if (bid < 1536) { src = Wv; dst = wtqkv + 1280 * 1024; s = bid - 1280; nlog = 3; }
    else                 { src = Wo; dst = wto;                 s = bid - 1536; nlog = 5; }
    int N  = 32 << nlog;
    int k0 = (s >> nlog) * 32, n0 = (s & ((1 << nlog) - 1)) * 32;
    int lr = threadIdx.x >> 5, lc = threadIdx.x & 31;
    #pragma unroll
    for (int i = 0; i < 4; i++) {
        int r = lr + i * 8;
        tile[r][lc] = src[(k0 + r) * N + n0 + lc];
    }
    __syncthreads();
    #pragma unroll
    for (int i = 0; i < 4; i++) {
        int r = lr + i * 8;
        dst[(n0 + r) * 1024 + k0 + lc] = f2bf(tile[lc][r]);
    }
}

// ------------------------------------------------ 128x128 bf16 MFMA GEMM (m97 structure)
// C = A (Mx K) * Bt^T (N x K); global_load_lds width-16 staging, BK=32
template <typename T>
__global__ __launch_bounds__(256) void gemm128_kernel(const unsigned short* __restrict__ A,
                                                      const unsigned short* __restrict__ Bt,
                                                      T* __restrict__ Cm, int Ni, int Ki) {
    __shared__ __align__(16) unsigned short As[128 * 32];
    __shared__ __align__(16) unsigned short Bs[128 * 32];
    int m0 = blockIdx.x * 128, n0 = blockIdx.y * 128;
    int tid = threadIdx.x;
    int w = tid >> 6, lane = tid & 63;
    int col = lane & 15, quad = lane >> 4;
    int wm = (w >> 1) * 64, wn = (w & 1) * 64;
    int srow0 = w * 32 + (lane >> 2);     // + j*16
    int skoff = (lane & 3) * 8;

    f32x4 acc[4][4];
    #pragma unroll
    for (int mt = 0; mt < 4; mt++)
        #pragma unroll
        for (int nt = 0; nt < 4; nt++) acc[mt][nt] = (f32x4){0.f, 0.f, 0.f, 0.f};

    for (int k0 = 0; k0 < Ki; k0 += 32) {
        #pragma unroll
        for (int j = 0; j < 2; j++) {
            int r = srow0 + j * 16;
            __builtin_amdgcn_global_load_lds(
                (const __attribute__((address_space(1))) unsigned int*)(A + (size_t)(m0 + r) * Ki + k0 + skoff),
                (__attribute__((address_space(3))) unsigned int*)(As + r * 32 + skoff), 16, 0, 0);
            __builtin_amdgcn_global_load_lds(
                (const __attribute__((address_space(1))) unsigned int*)(Bt + (size_t)(n0 + r) * Ki + k0 + skoff),
                (__attribute__((address_space(3))) unsigned int*)(Bs + r * 32 + skoff), 16, 0, 0);
        }
        __syncthreads();
        bf16x8 af[4], bfr[4];
        #pragma unroll
        for (int mt = 0; mt < 4; mt++) af[mt]  = *(const bf16x8*)&As[(wm + mt * 16 + col) * 32 + quad * 8];
        #pragma unroll
        for (int nt = 0; nt < 4; nt++) bfr[nt] = *(const bf16x8*)&Bs[(wn + nt * 16 + col) * 32 + quad * 8];
        #pragma unroll
        for (int mt = 0; mt < 4; mt++)
            #pragma unroll
            for (int nt = 0; nt < 4; nt++)
                acc[mt][nt] = __builtin_amdgcn_mfma_f32_16x16x32_bf16(af[mt], bfr[nt], acc[mt][nt], 0, 0, 0);
        __syncthreads();
    }
    #pragma unroll
    for (int mt = 0; mt < 4; mt++)
        #pragma unroll
        for (int nt = 0; nt < 4; nt++)
            #pragma unroll
            for (int r = 0; r < 4; r++) {
                size_t idx = (size_t)(m0 + wm + mt * 16 + quad * 4 + r) * Ni + n0 + wn + nt * 16 + col;
                if constexpr (sizeof(T) == 2) Cm[idx] = f2bf(acc[mt][nt][r]);
                else                          Cm[idx] = acc[mt][nt][r];
            }
}

// ------------------------------------------------ RoPE + RMSNorm on q (*0.125) + k, in-place bf16
__global__ void rope_rms_kernel(unsigned short* __restrict__ qkvb,
                                const float* __restrict__ cosb, const float* __restrict__ sinb) {
    int rid  = blockIdx.x * 4 + (threadIdx.x >> 6);
    int lane = threadIdx.x & 63;
    int token = rid / 20, head = rid % 20;     // 20 = H + KV
    int t = token & (T_ - 1);
    unsigned short* p = qkvb + (size_t)token * NQKV_ + head * 64;
    int i  = lane & 31;
    float c = cosb[t * 32 + i], s = sinb[t * 32 + i];
    float out;
    if (lane < 32) {
        float x1 = bf2f(p[lane]), x2 = bf2f(p[lane + 32]);
        out = x1 * c + x2 * s;
    } else {
        float x1 = bf2f(p[lane - 32]), x2 = bf2f(p[lane]);
        out = -x1 * s + x2 * c;
    }
    float sq = out * out;
    #pragma unroll
    for (int msk = 1; msk < 64; msk <<= 1) sq += __shfl_xor(sq, msk, 64);
    float r = rsqrtf(sq * (1.0f / 64.0f) + 1e-6f);
    float scale = (head < H_) ? 0.125f : 1.0f;
    p[lane] = f2bf(out * r * scale);
}

// ------------------------------------------------ V -> V^T global: vtb[(b*KV+kvh)][d][t]
__global__ __launch_bounds__(256) void vtrans_kernel(const unsigned short* __restrict__ qkvb,
                                                     unsigned short* __restrict__ vtb) {
    __shared__ unsigned short tileb[64][72];
    int tile = blockIdx.x & 31;     // T/64
    int bkv  = blockIdx.x >> 5;     // 0..7
    int b = bkv >> 2, kvh = bkv & 3;
    int tid = threadIdx.x;
    int t0 = tile * 64;
    #pragma unroll
    for (int i = 0; i < 2; i++) {
        int idx = tid + i * 256;
        int r = idx >> 3, d8 = (idx & 7) * 8;
        *(uint4*)&tileb[r][d8] =
            *(const uint4*)&qkvb[(size_t)(b * T_ + t0 + r) * NQKV_ + 1280 + kvh * 64 + d8];
    }
    __syncthreads();
    #pragma unroll
    for (int i = 0; i < 2; i++) {
        int idx = tid + i * 256;
        int dr = idx >> 3, t8 = (idx & 7) * 8;
        unsigned short tmp[8];
        #pragma unroll
        for (int j = 0; j < 8; j++) tmp[j] = tileb[t8 + j][dr];
        *(uint4*)&vtb[((size_t)(bkv * 64 + dr)) * T_ + t0 + t8] = *(uint4*)tmp;
    }
}

// ------------------------------------------------ MFMA flash attention
// block = (b, h, tile-pair p): processes q-tiles p and 31-p  (qt+1 sums to 33 -> balanced)
// 4 waves; wave w owns query rows w*16..+15; K/V^T double-buffered, 1 barrier/iter
__global__ __launch_bounds__(256) void attn_kernel(const unsigned short* __restrict__ qkvb,
                                                   const unsigned short* __restrict__ vtb,
                                                   unsigned short* __restrict__ yb) {
    __shared__ __align__(16) unsigned short Qs[64 * ST_];
    __shared__ __align__(16) unsigned short Ks[2][64 * ST_];
    __shared__ __align__(16) unsigned short Vts[2][64 * ST_];
    __shared__ __align__(16) unsigned short Ps[64 * ST_];

    int p  = blockIdx.x & 15;
    int bh = blockIdx.x >> 4;
    int b = bh >> 4, h = bh & 15, kvh = h >> 2;
    int tid = threadIdx.x;
    int w = tid >> 6, lane = tid & 63;
    int col = lane & 15, quad = lane >> 4;

    // staging indices (all 256 threads): K tile rows sr,(sr+32); V^T same
    int sr = tid >> 3;
    int sd = (tid & 7) * 8;
    size_t kbase = (size_t)(b * T_) * NQKV_ + 1024 + kvh * 64;
    size_t vbase = (size_t)((b * KV_ + kvh) * 64) * T_;

    // Q staging: wave-private rows w*16..+15 (no cross-wave dependency)
    int qr = w * 16 + (lane >> 2);
    int qd = (lane & 3) * 8;

    #pragma unroll
    for (int ph = 0; ph < 2; ph++) {
        int qt   = ph ? (31 - p) : p;
        int tau0 = qt * 64;

        #pragma unroll
        for (int c = 0; c < 2; c++)
            *(uint4*)&Qs[qr * ST_ + qd + c * 32] =
                *(const uint4*)&qkvb[(size_t)(b * T_ + tau0 + qr) * NQKV_ + h * 64 + qd + c * 32];

        float mrow[4], lrow[4];
        #pragma unroll
        for (int r = 0; r < 4; r++) { mrow[r] = -1e30f; lrow[r] = 0.f; }
        f32x4 o[4];
        #pragma unroll
        for (int nt = 0; nt < 4; nt++) o[nt] = (f32x4){0.f, 0.f, 0.f, 0.f};

        // preload + stage tile 0 (previous phase's readers finished at its last barrier)
        uint4 kreg[2], vreg[2];
        #pragma unroll
        for (int i = 0; i < 2; i++) {
            kreg[i] = *(const uint4*)&qkvb[kbase + (size_t)(sr + i * 32) * NQKV_ + sd];
            vreg[i] = *(const uint4*)&vtb[vbase + (size_t)(sr + i * 32) * T_ + sd];
        }
        #pragma unroll
        for (int i = 0; i < 2; i++) {
            *(uint4*)&Ks[0][(sr + i * 32) * ST_ + sd]  = kreg[i];
            *(uint4*)&Vts[0][(sr + i * 32) * ST_ + sd] = vreg[i];
        }
        __syncthreads();

        for (int kt = 0; kt <= qt; kt++) {
            int cur = kt & 1;
            if (kt < qt) {   // prefetch next tile into regs (hidden behind MFMA)
                #pragma unroll
                for (int i = 0; i < 2; i++) {
                    kreg[i] = *(const uint4*)&qkvb[kbase + (size_t)((kt + 1) * 64 + sr + i * 32) * NQKV_ + sd];
                    vreg[i] = *(const uint4*)&vtb[vbase + (size_t)(sr + i * 32) * T_ + (kt + 1) * 64 + sd];
                }
            }
            // S = Q K^T (16 q-rows x 64 keys per wave)
            f32x4 sacc[4];
            #pragma unroll
            for (int nt = 0; nt < 4; nt++) sacc[nt] = (f32x4){0.f, 0.f, 0.f, 0.f};
            #pragma unroll
            for (int step = 0; step < 2; step++) {
                bf16x8 a = *(const bf16x8*)&Qs[(w * 16 + col) * ST_ + quad * 8 + step * 32];
                #pragma unroll
                for (int nt = 0; nt < 4; nt++) {
                    bf16x8 kb = *(const bf16x8*)&Ks[cur][(nt * 16 + col) * ST_ + quad * 8 + step * 32];
                    sacc[nt] = __builtin_amdgcn_mfma_f32_16x16x32_bf16(a, kb, sacc[nt], 0, 0, 0);
                }
            }
            if (kt == qt) {
                #pragma unroll
                for (int nt = 0; nt < 4; nt++)
                    #pragma unroll
                    for (int r = 0; r < 4; r++)
                        if (nt * 16 + col > w * 16 + quad * 4 + r) sacc[nt][r] = -1e30f;
            }
            float alpha[4];
            #pragma unroll
            for (int r = 0; r < 4; r++) {
                float mx = fmaxf(fmaxf(sacc[0][r], sacc[1][r]), fmaxf(sacc[2][r], sacc[3][r]));
                mx = fmaxf(mx, __shfl_xor(mx, 1, 64));
                mx = fmaxf(mx, __shfl_xor(mx, 2, 64));
                mx = fmaxf(mx, __shfl_xor(mx, 4, 64));
                mx = fmaxf(mx, __shfl_xor(mx, 8, 64));
                float mnew = fmaxf(mrow[r], mx);
                alpha[r] = __expf(mrow[r] - mnew);
                float rs = 0.f;
                #pragma unroll
                for (int nt = 0; nt < 4; nt++) {
                    float pv = __expf(sacc[nt][r] - mnew);
                    sacc[nt][r] = pv;
                    rs += pv;
                }
                rs += __shfl_xor(rs, 1, 64);
                rs += __shfl_xor(rs, 2, 64);
                rs += __shfl_xor(rs, 4, 64);
                rs += __shfl_xor(rs, 8, 64);
                lrow[r] = lrow[r] * alpha[r] + rs;
                mrow[r] = mnew;
            }
            // P -> LDS (wave-private stripe; adjacent-ushort writes merge into dwords)
            #pragma unroll
            for (int nt = 0; nt < 4; nt++)
                #pragma unroll
                for (int r = 0; r < 4; r++)
                    Ps[(w * 16 + quad * 4 + r) * ST_ + nt * 16 + col] = f2bf(sacc[nt][r]);
            #pragma unroll
            for (int nt = 0; nt < 4; nt++)
                #pragma unroll
                for (int r = 0; r < 4; r++)
                    o[nt][r] *= alpha[r];
            // O += P V  (B = V^T rows, contiguous)
            #pragma unroll
            for (int step = 0; step < 2; step++) {
                bf16x8 a = *(const bf16x8*)&Ps[(w * 16 + col) * ST_ + quad * 8 + step * 32];
                #pragma unroll
                for (int nt = 0; nt < 4; nt++) {
                    bf16x8 vb = *(const bf16x8*)&Vts[cur][(nt * 16 + col) * ST_ + quad * 8 + step * 32];
                    o[nt] = __builtin_amdgcn_mfma_f32_16x16x32_bf16(a, vb, o[nt], 0, 0, 0);
                }
            }
            if (kt < qt) {   // stage prefetched tile into the other buffer
                #pragma unroll
                for (int i = 0; i < 2; i++) {
                    *(uint4*)&Ks[cur ^ 1][(sr + i * 32) * ST_ + sd]  = kreg[i];
                    *(uint4*)&Vts[cur ^ 1][(sr + i * 32) * ST_ + sd] = vreg[i];
                }
            }
            __syncthreads();
        }

        #pragma unroll
        for (int r = 0; r < 4; r++) {
            float inv = 1.0f / lrow[r];
            size_t row = (size_t)(b * T_ + tau0 + w * 16 + quad * 4 + r) * C_ + h * 64;
            #pragma unroll
            for (int nt = 0; nt < 4; nt++)
                yb[row + nt * 16 + col] = f2bf(o[nt][r] * inv);
        }
    }
}

// ---------------------------------------------------------------- launch
extern "C" void kernel_launch(void* const* d_in, const int* in_sizes, int n_in,
                              void* d_out, int out_size, void* d_ws, size_t ws_size,
                              hipStream_t stream) {
    const float* x    = (const float*)d_in[0];
    const float* cosb = (const float*)d_in[1];
    const float* sinb = (const float*)d_in[2];
    const float* Wq   = (const float*)d_in[3];
    const float* Wk   = (const float*)d_in[4];
    const float* Wv   = (const float*)d_in[5];
    const float* Wo   = (const float*)d_in[6];
    float* out = (float*)d_out;

    char* ws = (char*)d_ws;
    unsigned short* xb    = (unsigned short*)(ws);               // 8 MB (reused as yb later)
    unsigned short* yb    = (unsigned short*)(ws);               // alias: xb dead after QKV GEMM
    unsigned short* wtqkv = (unsigned short*)(ws + ( 8u << 20)); // 3 MB
    unsigned short* wto   = (unsigned short*)(ws + (11u << 20)); // 2 MB
    unsigned short* qkvb  = (unsigned short*)(ws + (13u << 20)); // 12 MB
    unsigned short* vtb   = (unsigned short*)(ws + (25u << 20)); // 2 MB

    cast_x_kernel<<<4096, 256, 0, stream>>>(x, xb);
    transpose4_kernel<<<2560, 256, 0, stream>>>(Wq, Wk, Wv, Wo, wtqkv, wto);
    gemm128_kernel<unsigned short><<<dim3(32, 12), 256, 0, stream>>>(xb, wtqkv, qkvb, NQKV_, C_);
    rope_rms_kernel<<<(M_ * 20) / 4, 256, 0, stream>>>(qkvb, cosb, sinb);
    vtrans_kernel<<<256, 256, 0, stream>>>(qkvb, vtb);
    attn_kernel<<<B_ * H_ * 16, 256, 0, stream>>>(qkvb, vtb, yb);
    gemm128_kernel<float><<<dim3(32, 8), 256, 0, stream>>>(yb, wto, out, C_, C_);
}